// Round 5
// baseline (118.243 us; speedup 1.0000x reference)
//
#include <hip/hip_runtime.h>

typedef int   v4i __attribute__((ext_vector_type(4)));
typedef float v4f __attribute__((ext_vector_type(4)));

#define N_ROWS   262144
#define IN_F     256
#define OUT_F    256
#define N_TILES  (N_ROWS / 16)      // 16384
#define GRID     2048
#define ITERS    (N_TILES / GRID)   // 8

// ---------------- prep: weight int32 -> int8, per-channel offset & scale ----
__global__ void qlin_prep(const int* __restrict__ w,
                          const int* __restrict__ bias,
                          const float* __restrict__ is,
                          const float* __restrict__ wsc,
                          const float* __restrict__ os,
                          const int* __restrict__ izp,
                          signed char* __restrict__ w8,
                          int* __restrict__ off,
                          float* __restrict__ scale) {
    int o = blockIdx.x;
    int k = threadIdx.x;
    int v = w[o * IN_F + k];
    w8[o * IN_F + k] = (signed char)v;
    __shared__ int red[256];
    red[k] = v;
    __syncthreads();
    for (int s = 128; s > 0; s >>= 1) {
        if (k < s) red[k] += red[k + s];
        __syncthreads();
    }
    if (k == 0) {
        off[o]   = bias[o] - izp[0] * red[0];
        scale[o] = is[0] * wsc[o] / os[0];
    }
}

// ---------------- main GEMM -------------------------------------------------
__device__ inline int pack4(v4i a) {
    return (a.x & 255) | ((a.y & 255) << 8) | ((a.z & 255) << 16) | (a.w << 24);
}

#define WAIT_VM(n) asm volatile("s_waitcnt vmcnt(" #n ")" ::: "memory")
#define BAR() __builtin_amdgcn_s_barrier()

__global__ __launch_bounds__(256, 3) void
qlin_main(const int* __restrict__ x,           // [N][256] int32
          const signed char* __restrict__ w8,  // [256][256] int8
          const int* __restrict__ off,         // [256]
          const float* __restrict__ scale,     // [256]
          const int* __restrict__ ozp,         // [1]
          int* __restrict__ out) {             // [N][256] int32 (int8 values)
    __shared__ int lbuf[3][4096];              // 3 x 16 KB x-tile buffers

    const int tid  = threadIdx.x;
    const int wid  = tid >> 6;
    const int lane = tid & 63;
    const int l15  = lane & 15;
    const int lg   = lane >> 4;
    const int chBase = wid * 64;

    // ---- persistent weight fragments (A-operand), scales, offsets ----------
    v4i Wf[4][4];
#pragma unroll
    for (int cf = 0; cf < 4; ++cf) {
        const signed char* wrow = w8 + (chBase + cf * 16 + l15) * IN_F + lg * 16;
#pragma unroll
        for (int kc = 0; kc < 4; ++kc)
            Wf[cf][kc] = *(const v4i*)(wrow + kc * 64);
    }
    v4i of4[4]; v4f sc4[4];
#pragma unroll
    for (int cf = 0; cf < 4; ++cf) {
        const int cb = chBase + cf * 16 + lg * 4;
        of4[cf] = *(const v4i*)(off + cb);
        sc4[cf] = *(const v4f*)(scale + cb);
    }
    const float ozpf = (float)ozp[0];

    // ---- per-lane swizzled LDS read offsets (XOR bank swizzle) -------------
    const int msk = (l15 & 7) << 4;            // byte mask, bits 4-6
    int coff[4];
#pragma unroll
    for (int u = 0; u < 4; ++u) coff[u] = (lg * 64 + 16 * u) ^ msk;
    const int rowbase = l15 * 1024;

    const int t0 = blockIdx.x;

    // stage tile (16 rows x 256 ints = 16 KB) into lbuf[b]; 4 issues/wave.
    // LDS write is linear (base + lane*16); swizzle applied on the GLOBAL
    // source address (rule #21: inverse-swizzle source + swizzle on read).
    auto stage = [&](int b, int it) {
        const char* base = (const char*)x + (size_t)(t0 + it * GRID) * (16 * IN_F * 4);
#pragma unroll
        for (int j = 0; j < 4; ++j) {
            const int c = wid * 4 + j;             // chunk = tile row (1 KB)
            const int m = (c & 7) << 4;
            const char* src = base + c * 1024 + ((lane * 16) ^ m);
            __builtin_amdgcn_global_load_lds(
                (const __attribute__((address_space(1))) unsigned int*)src,
                (__attribute__((address_space(3))) unsigned int*)&lbuf[b][c * 256],
                16, 0, 0);
        }
    };

    auto compute = [&](int b, int it) {
        const char* lp = (const char*)lbuf[b] + rowbase;
        v4i Xf[4];
#pragma unroll
        for (int kc = 0; kc < 4; ++kc) {
            v4i a0 = *(const v4i*)(lp + kc * 256 + coff[0]);
            v4i a1 = *(const v4i*)(lp + kc * 256 + coff[1]);
            v4i a2 = *(const v4i*)(lp + kc * 256 + coff[2]);
            v4i a3 = *(const v4i*)(lp + kc * 256 + coff[3]);
            v4i pk;
            pk.x = pack4(a0); pk.y = pack4(a1); pk.z = pack4(a2); pk.w = pack4(a3);
            Xf[kc] = pk;
        }
        v4i acc[4];
#pragma unroll
        for (int cf = 0; cf < 4; ++cf) acc[cf] = (v4i){0, 0, 0, 0};
#pragma unroll
        for (int kc = 0; kc < 4; ++kc)
#pragma unroll
            for (int cf = 0; cf < 4; ++cf)
                acc[cf] = __builtin_amdgcn_mfma_i32_16x16x64_i8(Wf[cf][kc], Xf[kc], acc[cf], 0, 0, 0);

        const int orow = ((t0 + it * GRID) * 16 + l15) * OUT_F;
#pragma unroll
        for (int cf = 0; cf < 4; ++cf) {
            v4i res;
#pragma unroll
            for (int r = 0; r < 4; ++r) {
                float v = (float)(acc[cf][r] + of4[cf][r]) * sc4[cf][r] + ozpf;
                v = rintf(v);
                v = fminf(fmaxf(v, -128.0f), 127.0f);
                res[r] = (int)v;
            }
            __builtin_nontemporal_store(res, (v4i*)(out + orow + chBase + cf * 16 + lg * 4));
        }
    };

    // ---- 3-deep pipelined loop, counted vmcnt (4 loads + 4 stores / iter) --
    // Buffers cycle tile t -> buf t%3. Waits derived by op-count (in-order
    // vmcnt retirement): see per-line comments.
    stage(0, 0);
    stage(1, 1);
    stage(2, 2);

    WAIT_VM(8);  BAR();   // out: L0,L1,L2(12) -> need L0, leave L1,L2
    compute(0, 0);
    BAR();
    stage(0, 3);

    WAIT_VM(12); BAR();   // out: L1,L2,S0,L3(16) -> need L1, leave 12
    compute(1, 1);
    BAR();
    stage(1, 4);

    WAIT_VM(16); BAR();   // out: L2,S0,L3,S1,L4(20) -> need L2, leave 16
    compute(2, 2);
    BAR();
    stage(2, 5);

    WAIT_VM(16); BAR();   // out: S0,L3,S1,L4,S2,L5(24) -> need L3, leave 16
    compute(0, 3);
    BAR();
    stage(0, 6);

    WAIT_VM(16); BAR();   // out: S1,L4,S2,L5,S3,L6(24) -> need L4, leave 16
    compute(1, 4);
    BAR();
    stage(1, 7);

    WAIT_VM(16); BAR();   // out: S2,L5,S3,L6,S4,L7(24) -> need L5, leave 16
    compute(2, 5);
    BAR();

    WAIT_VM(12); BAR();   // out: S3,L6,S4,L7,S5(20) -> need L6, leave 12
    compute(0, 6);
    BAR();

    WAIT_VM(8);  BAR();   // out: S4,L7,S5,S6(16) -> need L7, leave 8
    compute(1, 7);
}

extern "C" void kernel_launch(void* const* d_in, const int* in_sizes, int n_in,
                              void* d_out, int out_size, void* d_ws, size_t ws_size,
                              hipStream_t stream) {
    const int*   x   = (const int*)d_in[0];
    const int*   w   = (const int*)d_in[1];
    const int*   b   = (const int*)d_in[2];
    const float* is  = (const float*)d_in[3];
    const float* wsc = (const float*)d_in[4];
    const float* os  = (const float*)d_in[5];
    const int*   izp = (const int*)d_in[6];
    const int*   ozp = (const int*)d_in[7];
    int* out = (int*)d_out;

    signed char* w8    = (signed char*)d_ws;                 // 65536 B
    int*         off   = (int*)((char*)d_ws + 65536);        // 1024 B
    float*       scale = (float*)((char*)d_ws + 66560);      // 1024 B

    qlin_prep<<<256, 256, 0, stream>>>(w, b, is, wsc, os, izp, w8, off, scale);
    qlin_main<<<GRID, 256, 0, stream>>>(x, w8, off, scale, ozp, out);
}

// Round 6
// 113.920 us; speedup vs baseline: 1.0379x; 1.0379x over previous
//
#include <hip/hip_runtime.h>

typedef int   v4i __attribute__((ext_vector_type(4)));
typedef float v4f __attribute__((ext_vector_type(4)));

#define N_ROWS   262144
#define IN_F     256
#define OUT_F    256
#define N_TILES  (N_ROWS / 16)      // 16384
#define GRID     2048
#define ITERS    (N_TILES / GRID)   // 8

// ---------------- prep: weight int32 -> int8, per-channel offset & scale ----
__global__ void qlin_prep(const int* __restrict__ w,
                          const int* __restrict__ bias,
                          const float* __restrict__ is,
                          const float* __restrict__ wsc,
                          const float* __restrict__ os,
                          const int* __restrict__ izp,
                          signed char* __restrict__ w8,
                          int* __restrict__ off,
                          float* __restrict__ scale) {
    int o = blockIdx.x;
    int k = threadIdx.x;
    int v = w[o * IN_F + k];
    w8[o * IN_F + k] = (signed char)v;
    __shared__ int red[256];
    red[k] = v;
    __syncthreads();
    for (int s = 128; s > 0; s >>= 1) {
        if (k < s) red[k] += red[k + s];
        __syncthreads();
    }
    if (k == 0) {
        off[o]   = bias[o] - izp[0] * red[0];
        scale[o] = is[0] * wsc[o] / os[0];
    }
}

// ---------------- main GEMM -------------------------------------------------
__device__ inline int pack4(v4i a) {
    return (a.x & 255) | ((a.y & 255) << 8) | ((a.z & 255) << 16) | (a.w << 24);
}

#define WAIT_VM(n) asm volatile("s_waitcnt vmcnt(" #n ")" ::: "memory")
#define BAR()  __builtin_amdgcn_s_barrier()
#define SB0()  __builtin_amdgcn_sched_barrier(0)

__global__ __launch_bounds__(256, 3) void
qlin_main(const int* __restrict__ x,           // [N][256] int32
          const signed char* __restrict__ w8,  // [256][256] int8
          const int* __restrict__ off,         // [256]
          const float* __restrict__ scale,     // [256]
          const int* __restrict__ ozp,         // [1]
          int* __restrict__ out) {             // [N][256] int32 (int8 values)
    __shared__ int lbuf[3][4096];              // 3 x 16 KB x-tile buffers

    const int tid  = threadIdx.x;
    const int wid  = tid >> 6;
    const int lane = tid & 63;
    const int l15  = lane & 15;
    const int lg   = lane >> 4;
    const int chBase = wid * 64;

    // ---- persistent weight fragments (A-operand), scales, offsets ----------
    v4i Wf[4][4];
#pragma unroll
    for (int cf = 0; cf < 4; ++cf) {
        const signed char* wrow = w8 + (chBase + cf * 16 + l15) * IN_F + lg * 16;
#pragma unroll
        for (int kc = 0; kc < 4; ++kc)
            Wf[cf][kc] = *(const v4i*)(wrow + kc * 64);
    }
    v4i of4[4]; v4f sc4[4];
#pragma unroll
    for (int cf = 0; cf < 4; ++cf) {
        const int cb = chBase + cf * 16 + lg * 4;
        of4[cf] = *(const v4i*)(off + cb);
        sc4[cf] = *(const v4f*)(scale + cb);
    }
    const float ozpf = (float)ozp[0];

    // ---- per-lane swizzled LDS read offsets (XOR bank swizzle) -------------
    const int msk = (l15 & 7) << 4;
    int coff[4];
#pragma unroll
    for (int u = 0; u < 4; ++u) coff[u] = (lg * 64 + 16 * u) ^ msk;
    const int rowbase = l15 * 1024;

    const int t0 = blockIdx.x;

    // stage tile (16 rows x 1 KB) into lbuf[b]; LDS dest linear, XOR swizzle
    // applied on the GLOBAL source (rule #21).
    auto stage = [&](int b, int it) {
        const char* base = (const char*)x + (size_t)(t0 + it * GRID) * (16 * IN_F * 4);
#pragma unroll
        for (int j = 0; j < 4; ++j) {
            const int c = wid * 4 + j;
            const int m = (c & 7) << 4;
            const char* src = base + c * 1024 + ((lane * 16) ^ m);
            __builtin_amdgcn_global_load_lds(
                (const __attribute__((address_space(1))) unsigned int*)src,
                (__attribute__((address_space(3))) unsigned int*)&lbuf[b][c * 256],
                16, 0, 0);
        }
    };

    v4i res[4];  // epilogue results held across the barrier, stored late

    auto compute = [&](int b) {
        const char* lp = (const char*)lbuf[b] + rowbase;
        v4i Xf[4];
#pragma unroll
        for (int kc = 0; kc < 4; ++kc) {
            v4i a0 = *(const v4i*)(lp + kc * 256 + coff[0]);
            v4i a1 = *(const v4i*)(lp + kc * 256 + coff[1]);
            v4i a2 = *(const v4i*)(lp + kc * 256 + coff[2]);
            v4i a3 = *(const v4i*)(lp + kc * 256 + coff[3]);
            v4i pk;
            pk.x = pack4(a0); pk.y = pack4(a1); pk.z = pack4(a2); pk.w = pack4(a3);
            Xf[kc] = pk;
        }
        v4i acc[4];
#pragma unroll
        for (int cf = 0; cf < 4; ++cf) acc[cf] = (v4i){0, 0, 0, 0};
#pragma unroll
        for (int kc = 0; kc < 4; ++kc)
#pragma unroll
            for (int cf = 0; cf < 4; ++cf)
                acc[cf] = __builtin_amdgcn_mfma_i32_16x16x64_i8(Wf[cf][kc], Xf[kc], acc[cf], 0, 0, 0);
#pragma unroll
        for (int cf = 0; cf < 4; ++cf) {
#pragma unroll
            for (int r = 0; r < 4; ++r) {
                float v = (float)(acc[cf][r] + of4[cf][r]) * sc4[cf][r] + ozpf;
                v = rintf(v);
                v = fminf(fmaxf(v, -128.0f), 127.0f);
                res[cf][r] = (int)v;
            }
        }
    };

    auto store_res = [&](int it) {
        const int orow = ((t0 + it * GRID) * 16 + l15) * OUT_F + chBase + lg * 4;
#pragma unroll
        for (int cf = 0; cf < 4; ++cf)
            *(v4i*)(out + orow + cf * 16) = res[cf];
    };

    // ---- 3-deep pipeline; stores issued AFTER next stage so vmcnt waits
    // before compute() drain loads only (stores are younger). Waits derived
    // by in-order retirement op-count; per-line comments list outstanding.
    stage(0, 0);
    stage(1, 1);
    stage(2, 2);

    WAIT_VM(8);  BAR();   // L0,L1,L2(12): need L0 -> leave L1,L2 = 8
    compute(0);
    BAR(); SB0();
    stage(0, 3); SB0();   // +L3
    store_res(0); SB0();  // +S0   outstanding: L1,L2,L3,S0 = 16

    WAIT_VM(12); BAR();   // need L1 -> leave L2,L3,S0 = 12
    compute(1);
    BAR(); SB0();
    stage(1, 4); SB0();
    store_res(1); SB0();  // outstanding: L2,L3,S0,L4,S1 = 20

    WAIT_VM(16); BAR();   // need L2 -> leave L3,S0,L4,S1 = 16
    compute(2);
    BAR(); SB0();
    stage(2, 5); SB0();
    store_res(2); SB0();  // outstanding: L3,S0,L4,S1,L5,S2 = 24

    WAIT_VM(20); BAR();   // need L3 -> leave S0,L4,S1,L5,S2 = 20
    compute(0);
    BAR(); SB0();
    stage(0, 6); SB0();
    store_res(3); SB0();  // outstanding: S0,L4,S1,L5,S2,L6,S3 = 28

    WAIT_VM(20); BAR();   // need L4 (drain S0 too) -> leave S1,L5,S2,L6,S3 = 20
    compute(1);
    BAR(); SB0();
    stage(1, 7); SB0();
    store_res(4); SB0();  // outstanding: S1,L5,S2,L6,S3,L7,S4 = 28

    WAIT_VM(20); BAR();   // need L5 (drain S1) -> leave S2,L6,S3,L7,S4 = 20
    compute(2);
    BAR(); SB0();
    store_res(5); SB0();  // outstanding: S2,L6,S3,L7,S4,S5 = 24

    WAIT_VM(16); BAR();   // need L6 (drain S2) -> leave S3,L7,S4,S5 = 16
    compute(0);
    BAR(); SB0();
    store_res(6); SB0();  // outstanding: S3,L7,S4,S5,S6 = 20

    WAIT_VM(12); BAR();   // need L7 (drain S3) -> leave S4,S5,S6 = 12
    compute(1);
    store_res(7);
}

extern "C" void kernel_launch(void* const* d_in, const int* in_sizes, int n_in,
                              void* d_out, int out_size, void* d_ws, size_t ws_size,
                              hipStream_t stream) {
    const int*   x   = (const int*)d_in[0];
    const int*   w   = (const int*)d_in[1];
    const int*   b   = (const int*)d_in[2];
    const float* is  = (const float*)d_in[3];
    const float* wsc = (const float*)d_in[4];
    const float* os  = (const float*)d_in[5];
    const int*   izp = (const int*)d_in[6];
    const int*   ozp = (const int*)d_in[7];
    int* out = (int*)d_out;

    signed char* w8    = (signed char*)d_ws;                 // 65536 B
    int*         off   = (int*)((char*)d_ws + 65536);        // 1024 B
    float*       scale = (float*)((char*)d_ws + 66560);      // 1024 B

    qlin_prep<<<256, 256, 0, stream>>>(w, b, is, wsc, os, izp, w8, off, scale);
    qlin_main<<<GRID, 256, 0, stream>>>(x, w8, off, scale, ozp, out);
}